// Round 1
// baseline (269.689 us; speedup 1.0000x reference)
//
#include <hip/hip_runtime.h>
#include <math.h>

#define NB 8
#define NF 16384
#define NH 256
#define CL 128                 // chunk length (steps)
#define CPB (NF / CL)          // 128 chunks per batch
#define NCHUNK (NB * CPB)      // 1024 chunks
#define NROW (NB * NF)         // 131072 rows
#define ROWS 2                 // rows per MLP thread

#define GX 0.0f
#define GY 0.0f
#define GZ -9.81007f

// ws layout (in floats):
//  rec:   NROW*8   floats  (chunk-interleaved records: [i*NCHUNK+chunk]*8 = ca3,cg3,dt,pad)
//  summ:  NCHUNK*16 floats (P4, T,S,Ux,Uy, Uz,Wx,Wy,Wz, pad4)
//  state: NCHUNK*16 floats (px,py,pz,vx, vy,vz,qw,qx, qy,qz,pad,pad, pad4)
#define REC_OFF   0
#define SUMM_OFF  ((size_t)NROW * 8)
#define STATE_OFF ((size_t)NROW * 8 + (size_t)NCHUNK * 16)

__device__ __forceinline__ void qrotate(float qw, float qx, float qy, float qz,
                                        float vx, float vy, float vz,
                                        float& ox, float& oy, float& oz) {
    // t = cross(qv, v) + qw*v ; out = v + 2*cross(qv, t)
    float tx = qy*vz - qz*vy + qw*vx;
    float ty = qz*vx - qx*vz + qw*vy;
    float tz = qx*vy - qy*vx + qw*vz;
    ox = vx + 2.0f*(qy*tz - qz*ty);
    oy = vy + 2.0f*(qz*tx - qx*tz);
    oz = vz + 2.0f*(qx*ty - qy*tx);
}

__device__ __forceinline__ void qmulf(float aw, float ax, float ay, float az,
                                      float bw, float bx, float by, float bz,
                                      float& ow, float& ox, float& oy, float& oz) {
    ow = aw*bw - ax*bx - ay*by - az*bz;
    ox = aw*bx + bw*ax + (ay*bz - az*by);
    oy = aw*by + bw*ay + (az*bx - ax*bz);
    oz = aw*bz + bw*az + (ax*by - ay*bx);
}

// quat_exp(v) with Taylor series exact to fp32 for |v| < ~0.3 (here |v| <= ~0.02).
// Matches reference: w = cos(theta/2), sinc = sin(theta/2)/theta, incl. the 1e-16 shift.
__device__ __forceinline__ void qexpf3(float vx, float vy, float vz,
                                       float& ew, float& ex, float& ey, float& ez) {
    float th2 = vx*vx + vy*vy + vz*vz + 1e-16f;
    float h2  = 0.25f * th2;                       // (theta/2)^2
    ew = 1.0f + h2*(-0.5f + h2*((1.0f/24.0f) - h2*(1.0f/720.0f)));
    float sh = 0.5f + h2*(-(1.0f/12.0f) + h2*(1.0f/240.0f));
    ex = vx*sh; ey = vy*sh; ez = vz*sh;
}

__device__ __forceinline__ float gelu_tanh(float h) {
    float h3 = h*h*h;
    float u  = 0.7978845608028654f * (h + 0.044715f*h3);
    // tanh(u) = 1 - 2/(1+exp(2u)); exp overflow -> inf -> t=1 (correct saturation)
    float t = 1.0f - __fdividef(2.0f, 1.0f + __expf(2.0f*u));
    return 0.5f*h*(1.0f + t);
}

// ---------------- Kernel 1: MLP (correction) + record packing ----------------
__global__ __launch_bounds__(256, 2)
void mlp_kernel(const float* __restrict__ acc, const float* __restrict__ gyro,
                const float* __restrict__ dt,
                const float* __restrict__ Wenc, const float* __restrict__ benc,
                const float* __restrict__ Wdec, const float* __restrict__ bdec,
                float* __restrict__ out, float* __restrict__ rec) {
    __shared__ float4 wlds[NH*4];
    {
        int j = threadIdx.x;   // blockDim.x == 256 == NH
        float w0 = Wenc[0*NH+j], w1 = Wenc[1*NH+j], w2 = Wenc[2*NH+j];
        float w3 = Wenc[3*NH+j], w4 = Wenc[4*NH+j], w5 = Wenc[5*NH+j];
        float bb = benc[j];
        float d0 = Wdec[j*6+0], d1 = Wdec[j*6+1], d2 = Wdec[j*6+2];
        float d3 = Wdec[j*6+3], d4 = Wdec[j*6+4], d5 = Wdec[j*6+5];
        wlds[j*4+0] = make_float4(w0, w1, w2, w3);
        wlds[j*4+1] = make_float4(w4, w5, bb, 0.0f);
        wlds[j*4+2] = make_float4(d0, d1, d2, d3);
        wlds[j*4+3] = make_float4(d4, d5, 0.0f, 0.0f);
    }
    __syncthreads();

    float bd0 = bdec[0], bd1 = bdec[1], bd2 = bdec[2];
    float bd3 = bdec[3], bd4 = bdec[4], bd5 = bdec[5];

    int tid = blockIdx.x * 256 + threadIdx.x;
    #pragma unroll
    for (int rr = 0; rr < ROWS; rr++) {
        int n = tid + rr * (NROW / ROWS);
        float ax = acc[n*3+0], ay = acc[n*3+1], az = acc[n*3+2];
        float gx = gyro[n*3+0], gy = gyro[n*3+1], gz = gyro[n*3+2];
        float dtv = dt[n];
        float c0 = bd0, c1 = bd1, c2 = bd2, c3 = bd3, c4 = bd4, c5 = bd5;
        #pragma unroll 4
        for (int j = 0; j < NH; j++) {
            float4 wa  = wlds[j*4+0];
            float4 wb  = wlds[j*4+1];
            float4 wd0 = wlds[j*4+2];
            float4 wd1 = wlds[j*4+3];
            float h = wb.z + wa.x*ax + wa.y*ay + wa.z*az + wa.w*gx + wb.x*gy + wb.y*gz;
            float g = gelu_tanh(h);
            c0 += g*wd0.x; c1 += g*wd0.y; c2 += g*wd0.z;
            c3 += g*wd0.w; c4 += g*wd1.x; c5 += g*wd1.y;
        }
        // correction -> out channels 10..15
        float* ob = out + (size_t)n*16;
        *(float2*)(ob+10) = make_float2(c0, c1);
        *(float4*)(ob+12) = make_float4(c2, c3, c4, c5);
        // corrected acc/gyro + dt -> interleaved record
        int b = n / NF, f = n % NF;
        int chunk = b*CPB + (f / CL), ii = f % CL;
        float4* rp = (float4*)rec + (size_t)(ii*NCHUNK + chunk)*2;
        rp[0] = make_float4(c0+ax, c1+ay, c2+az, c3+gx);
        rp[1] = make_float4(c4+gy, c5+gz, dtv, 0.0f);
    }
}

// ---------------- Kernel 2: per-chunk summaries (Phase A) ----------------
__global__ __launch_bounds__(64, 1)
void phaseA(const float* __restrict__ rec, float* __restrict__ summ) {
    int c = blockIdx.x * 64 + threadIdx.x;
    if (c >= NCHUNK) return;
    float Pw = 1.0f, Px = 0.0f, Py = 0.0f, Pz = 0.0f;
    float Ux = 0, Uy = 0, Uz = 0, Wx = 0, Wy = 0, Wz = 0, T = 0, S = 0;
    const float4* r = (const float4*)rec;
    #pragma unroll 4
    for (int i = 0; i < CL; i++) {
        float4 r0 = r[(size_t)(i*NCHUNK + c)*2];
        float4 r1 = r[(size_t)(i*NCHUNK + c)*2 + 1];
        float cax = r0.x, cay = r0.y, caz = r0.z;
        float cgx = r0.w, cgy = r1.x, cgz = r1.y;
        float dtv = r1.z;
        // u = R(P) ca  (P = local prefix before step i)
        float ux, uy, uz;
        qrotate(Pw, Px, Py, Pz, cax, cay, caz, ux, uy, uz);
        float hdt2 = 0.5f*dtv*dtv;
        // position contribution uses exclusive U,T
        Wx += Ux*dtv + ux*hdt2;  Wy += Uy*dtv + uy*hdt2;  Wz += Uz*dtv + uz*hdt2;
        S  += T*dtv + hdt2;
        Ux += ux*dtv; Uy += uy*dtv; Uz += uz*dtv;
        T  += dtv;
        // P = P (x) exp(cg*dt)
        float ew, ex, ey, ez;
        qexpf3(cgx*dtv, cgy*dtv, cgz*dtv, ew, ex, ey, ez);
        float nw, nx, ny, nz;
        qmulf(Pw, Px, Py, Pz, ew, ex, ey, ez, nw, nx, ny, nz);
        Pw = nw; Px = nx; Py = ny; Pz = nz;
    }
    float* s = summ + (size_t)c*16;
    ((float4*)s)[0] = make_float4(Pw, Px, Py, Pz);
    ((float4*)s)[1] = make_float4(T, S, Ux, Uy);
    ((float4*)s)[2] = make_float4(Uz, Wx, Wy, Wz);
}

// ---------------- Kernel 3: sequential combine per batch (Phase B) ----------------
__global__ __launch_bounds__(64, 1)
void phaseB(const float* __restrict__ summ, float* __restrict__ state,
            const float* __restrict__ init_pos, const float* __restrict__ init_vel,
            const float* __restrict__ init_rot) {
    int b = threadIdx.x;
    if (b >= NB) return;
    float px = init_pos[b*3+0], py = init_pos[b*3+1], pz = init_pos[b*3+2];
    float vx = init_vel[b*3+0], vy = init_vel[b*3+1], vz = init_vel[b*3+2];
    float qw = init_rot[b*4+0], qx = init_rot[b*4+1], qy = init_rot[b*4+2], qz = init_rot[b*4+3];
    #pragma unroll 2
    for (int ci = 0; ci < CPB; ci++) {
        int c = b*CPB + ci;
        float* st = state + (size_t)c*16;
        ((float4*)st)[0] = make_float4(px, py, pz, vx);
        ((float4*)st)[1] = make_float4(vy, vz, qw, qx);
        ((float4*)st)[2] = make_float4(qy, qz, 0.0f, 0.0f);
        const float* s = summ + (size_t)c*16;
        float4 s0 = ((const float4*)s)[0];
        float4 s1 = ((const float4*)s)[1];
        float4 s2 = ((const float4*)s)[2];
        float Pw = s0.x, Px = s0.y, Py = s0.z, Pz = s0.w;
        float T = s1.x, S = s1.y, Ux = s1.z, Uy = s1.w;
        float Uz = s2.x, Wx = s2.y, Wy = s2.z, Wz = s2.w;
        float RUx, RUy, RUz, RWx, RWy, RWz;
        qrotate(qw, qx, qy, qz, Ux, Uy, Uz, RUx, RUy, RUz);
        qrotate(qw, qx, qy, qz, Wx, Wy, Wz, RWx, RWy, RWz);
        px += vx*T + RWx + GX*S;
        py += vy*T + RWy + GY*S;
        pz += vz*T + RWz + GZ*S;
        vx += RUx + GX*T;
        vy += RUy + GY*T;
        vz += RUz + GZ*T;
        float nw, nx, ny, nz;
        qmulf(qw, qx, qy, qz, Pw, Px, Py, Pz, nw, nx, ny, nz);
        float inv = 1.0f / sqrtf(nw*nw + nx*nx + ny*ny + nz*nz);
        qw = nw*inv; qx = nx*inv; qy = ny*inv; qz = nz*inv;
    }
}

// ---------------- Kernel 4: replay + emit (Phase C) ----------------
__global__ __launch_bounds__(64, 1)
void phaseC(const float* __restrict__ rec, const float* __restrict__ state,
            float* __restrict__ out) {
    int c = blockIdx.x * 64 + threadIdx.x;
    if (c >= NCHUNK) return;
    int b = c / CPB, ci = c % CPB;
    const float* st = state + (size_t)c*16;
    float4 s0 = ((const float4*)st)[0];
    float4 s1 = ((const float4*)st)[1];
    float4 s2 = ((const float4*)st)[2];
    float px = s0.x, py = s0.y, pz = s0.z;
    float vx = s0.w, vy = s1.x, vz = s1.y;
    float qw = s1.z, qx = s1.w, qy = s2.x, qz = s2.y;
    const float4* r = (const float4*)rec;
    float* obase = out + (size_t)(b*NF + ci*CL) * 16;
    #pragma unroll 4
    for (int i = 0; i < CL; i++) {
        float4 r0 = r[(size_t)(i*NCHUNK + c)*2];
        float4 r1 = r[(size_t)(i*NCHUNK + c)*2 + 1];
        float cax = r0.x, cay = r0.y, caz = r0.z;
        float cgx = r0.w, cgy = r1.x, cgz = r1.y;
        float dtv = r1.z;
        // a_world = R(q) ca + G   (q before update)
        float awx, awy, awz;
        qrotate(qw, qx, qy, qz, cax, cay, caz, awx, awy, awz);
        awx += GX; awy += GY; awz += GZ;
        float hdt2 = 0.5f*dtv*dtv;
        px += vx*dtv + awx*hdt2;
        py += vy*dtv + awy*hdt2;
        pz += vz*dtv + awz*hdt2;
        vx += awx*dtv; vy += awy*dtv; vz += awz*dtv;
        // q = normalize(q (x) exp(cg*dt))
        float ew, ex, ey, ez;
        qexpf3(cgx*dtv, cgy*dtv, cgz*dtv, ew, ex, ey, ez);
        float nw, nx, ny, nz;
        qmulf(qw, qx, qy, qz, ew, ex, ey, ez, nw, nx, ny, nz);
        float inv = 1.0f / sqrtf(nw*nw + nx*nx + ny*ny + nz*nz);
        qw = nw*inv; qx = nx*inv; qy = ny*inv; qz = nz*inv;
        // emit post-update state: pos(3), vel(3), rot(4)
        float* ob = obase + (size_t)i*16;
        *(float4*)(ob+0) = make_float4(px, py, pz, vx);
        *(float4*)(ob+4) = make_float4(vy, vz, qw, qx);
        *(float2*)(ob+8) = make_float2(qy, qz);
    }
}

extern "C" void kernel_launch(void* const* d_in, const int* in_sizes, int n_in,
                              void* d_out, int out_size, void* d_ws, size_t ws_size,
                              hipStream_t stream) {
    const float* acc      = (const float*)d_in[0];
    const float* gyro     = (const float*)d_in[1];
    const float* dt       = (const float*)d_in[2];
    const float* init_pos = (const float*)d_in[3];
    const float* init_vel = (const float*)d_in[4];
    const float* init_rot = (const float*)d_in[5];
    const float* Wenc     = (const float*)d_in[6];
    const float* benc     = (const float*)d_in[7];
    const float* Wdec     = (const float*)d_in[8];
    const float* bdec     = (const float*)d_in[9];
    float* out = (float*)d_out;
    float* ws  = (float*)d_ws;
    float* rec   = ws + REC_OFF;
    float* summ  = ws + SUMM_OFF;
    float* state = ws + STATE_OFF;

    mlp_kernel<<<NROW/ROWS/256, 256, 0, stream>>>(acc, gyro, dt, Wenc, benc, Wdec, bdec, out, rec);
    phaseA<<<NCHUNK/64, 64, 0, stream>>>(rec, summ);
    phaseB<<<1, 64, 0, stream>>>(summ, state, init_pos, init_vel, init_rot);
    phaseC<<<NCHUNK/64, 64, 0, stream>>>(rec, state, out);
}

// Round 2
// 153.119 us; speedup vs baseline: 1.7613x; 1.7613x over previous
//
#include <hip/hip_runtime.h>
#include <math.h>

#define NB 8
#define NF 16384
#define NH 256
#define CL 8                   // steps per chunk
#define CPB (NF / CL)          // 2048 chunks per batch
#define NCHUNK (NB * CPB)      // 16384 chunks
#define NROW (NB * NF)         // 131072 rows
#define SPT (CPB / 256)        // 8 summaries per phaseB thread

#define GZ -9.81007f

// ws layout (floats):
//  summ:  NCHUNK*12   (P4, T,S,Ux,Uy, Uz,Wx,Wy,Wz)
//  state: NCHUNK*12   (px,py,pz,vx, vy,vz,qw,qx, qy,qz,pad,pad)
//  wpack: NH*16       (w0..w5, benc, d0..d5, pad3)  -- only live repack->mlp
#define SUMM_OFF   0
#define STATE_OFF  ((size_t)NCHUNK * 12)
#define WPACK_OFF  ((size_t)NCHUNK * 24)

__device__ __forceinline__ void qrotate(float qw, float qx, float qy, float qz,
                                        float vx, float vy, float vz,
                                        float& ox, float& oy, float& oz) {
    float tx = qy*vz - qz*vy + qw*vx;
    float ty = qz*vx - qx*vz + qw*vy;
    float tz = qx*vy - qy*vx + qw*vz;
    ox = vx + 2.0f*(qy*tz - qz*ty);
    oy = vy + 2.0f*(qz*tx - qx*tz);
    oz = vz + 2.0f*(qx*ty - qy*tx);
}

__device__ __forceinline__ void qmulf(float aw, float ax, float ay, float az,
                                      float bw, float bx, float by, float bz,
                                      float& ow, float& ox, float& oy, float& oz) {
    ow = aw*bw - ax*bx - ay*by - az*bz;
    ox = aw*bx + bw*ax + (ay*bz - az*by);
    oy = aw*by + bw*ay + (az*bx - ax*bz);
    oz = aw*bz + bw*az + (ax*by - ay*bx);
}

// quat_exp(w) for w = gyro*dt (|w| <= ~0.03): fp32-exact Taylor of
// cos(|w|/2) and sin(|w|/2)/|w|, including the reference's 1e-16 shift.
__device__ __forceinline__ void qexpw(float wx, float wy, float wz,
                                      float& ew, float& ex, float& ey, float& ez) {
    float th2 = wx*wx + wy*wy + wz*wz + 1e-16f;
    float h2  = 0.25f * th2;
    ew = 1.0f + h2*(-0.5f + h2*((1.0f/24.0f) - h2*(1.0f/720.0f)));
    float sh = 0.5f + h2*(-(1.0f/12.0f) + h2*(1.0f/240.0f));
    ex = wx*sh; ey = wy*sh; ez = wz*sh;
}

__device__ __forceinline__ float gelu_tanh(float h) {
    float h2 = h*h;
    float u2 = h*(1.5957691216057308f + 0.0713548162726009f*h2);  // 2*0.79788456*(h+0.044715h^3)
    float t  = 1.0f - __fdividef(2.0f, 1.0f + __expf(u2));
    float a  = 0.5f*h;
    return a + a*t;
}

// 12-float summary: P(4), T, S, U(3), W(3)
struct Sum {
    float Pw, Px, Py, Pz, T, S, Ux, Uy, Uz, Wx, Wy, Wz;
};

__device__ __forceinline__ Sum compose(const Sum& a, const Sum& b) {
    Sum r;
    float RUx, RUy, RUz, RWx, RWy, RWz;
    qrotate(a.Pw, a.Px, a.Py, a.Pz, b.Ux, b.Uy, b.Uz, RUx, RUy, RUz);
    qrotate(a.Pw, a.Px, a.Py, a.Pz, b.Wx, b.Wy, b.Wz, RWx, RWy, RWz);
    r.Ux = a.Ux + RUx;  r.Uy = a.Uy + RUy;  r.Uz = a.Uz + RUz;
    r.Wx = a.Wx + a.Ux*b.T + RWx;
    r.Wy = a.Wy + a.Uy*b.T + RWy;
    r.Wz = a.Wz + a.Uz*b.T + RWz;
    r.S  = a.S + a.T*b.T + b.S;
    r.T  = a.T + b.T;
    float nw, nx, ny, nz;
    qmulf(a.Pw, a.Px, a.Py, a.Pz, b.Pw, b.Px, b.Py, b.Pz, nw, nx, ny, nz);
    float inv = 1.0f / sqrtf(nw*nw + nx*nx + ny*ny + nz*nz);
    r.Pw = nw*inv; r.Px = nx*inv; r.Py = ny*inv; r.Pz = nz*inv;
    return r;
}

struct State { float px, py, pz, vx, vy, vz, qw, qx, qy, qz; };

__device__ __forceinline__ State applySum(const State& st, const Sum& s) {
    State r;
    float RUx, RUy, RUz, RWx, RWy, RWz;
    qrotate(st.qw, st.qx, st.qy, st.qz, s.Ux, s.Uy, s.Uz, RUx, RUy, RUz);
    qrotate(st.qw, st.qx, st.qy, st.qz, s.Wx, s.Wy, s.Wz, RWx, RWy, RWz);
    r.px = st.px + st.vx*s.T + RWx;
    r.py = st.py + st.vy*s.T + RWy;
    r.pz = st.pz + st.vz*s.T + RWz + GZ*s.S;
    r.vx = st.vx + RUx;
    r.vy = st.vy + RUy;
    r.vz = st.vz + RUz + GZ*s.T;
    float nw, nx, ny, nz;
    qmulf(st.qw, st.qx, st.qy, st.qz, s.Pw, s.Px, s.Py, s.Pz, nw, nx, ny, nz);
    float inv = 1.0f / sqrtf(nw*nw + nx*nx + ny*ny + nz*nz);
    r.qw = nw*inv; r.qx = nx*inv; r.qy = ny*inv; r.qz = nz*inv;
    return r;
}

// ---- Kernel 0: pack weights into 64B/hidden-unit records (SGPR-friendly) ----
__global__ void repack_kernel(const float* __restrict__ Wenc, const float* __restrict__ benc,
                              const float* __restrict__ Wdec, float* __restrict__ wp) {
    int j = threadIdx.x;
    float* p = wp + j*16;
    p[0] = Wenc[0*NH+j]; p[1] = Wenc[1*NH+j]; p[2] = Wenc[2*NH+j];
    p[3] = Wenc[3*NH+j]; p[4] = Wenc[4*NH+j]; p[5] = Wenc[5*NH+j];
    p[6] = benc[j];
    p[7]  = Wdec[j*6+0]; p[8]  = Wdec[j*6+1]; p[9]  = Wdec[j*6+2];
    p[10] = Wdec[j*6+3]; p[11] = Wdec[j*6+4]; p[12] = Wdec[j*6+5];
    p[13] = 0.0f; p[14] = 0.0f; p[15] = 0.0f;
}

// ---- Kernel 1: MLP correction -> out[...,10:16]. Weights via uniform s_load. ----
__global__ __launch_bounds__(256)
void mlp_kernel(const float* __restrict__ acc, const float* __restrict__ gyro,
                const float* __restrict__ wp, const float* __restrict__ bdec,
                float* __restrict__ out) {
    int n = blockIdx.x * 256 + threadIdx.x;
    float ax = acc[n*3+0], ay = acc[n*3+1], az = acc[n*3+2];
    float gx = gyro[n*3+0], gy = gyro[n*3+1], gz = gyro[n*3+2];
    float c0 = bdec[0], c1 = bdec[1], c2 = bdec[2];
    float c3 = bdec[3], c4 = bdec[4], c5 = bdec[5];
    #pragma unroll 4
    for (int j = 0; j < NH; j++) {
        const float* w = wp + j*16;   // uniform index -> scalar loads
        float h = w[6] + w[0]*ax + w[1]*ay + w[2]*az + w[3]*gx + w[4]*gy + w[5]*gz;
        float g = gelu_tanh(h);
        c0 += g*w[7];  c1 += g*w[8];  c2 += g*w[9];
        c3 += g*w[10]; c4 += g*w[11]; c5 += g*w[12];
    }
    float* ob = out + (size_t)n*16;
    *(float2*)(ob+10) = make_float2(c0, c1);
    *(float4*)(ob+12) = make_float4(c2, c3, c4, c5);
}

// ---- Kernel 2: per-chunk summaries ----
__global__ __launch_bounds__(64)
void phaseA(const float* __restrict__ out, const float* __restrict__ acc,
            const float* __restrict__ gyro, const float* __restrict__ dtp,
            float* __restrict__ summ) {
    int c = blockIdx.x * 64 + threadIdx.x;
    int b = c / CPB, ci = c % CPB;
    int row0 = b*NF + ci*CL;
    float Pw = 1.0f, Px = 0, Py = 0, Pz = 0;
    float T = 0, S = 0, Ux = 0, Uy = 0, Uz = 0, Wx = 0, Wy = 0, Wz = 0;
    #pragma unroll
    for (int i = 0; i < CL; i++) {
        int n = row0 + i;
        const float* ob = out + (size_t)n*16;
        float2 cA = *(const float2*)(ob+10);
        float4 cB = *(const float4*)(ob+12);
        float dtv = dtp[n];
        float cax = acc[n*3+0] + cA.x;
        float cay = acc[n*3+1] + cA.y;
        float caz = acc[n*3+2] + cB.x;
        float wx = (gyro[n*3+0] + cB.y)*dtv;
        float wy = (gyro[n*3+1] + cB.z)*dtv;
        float wz = (gyro[n*3+2] + cB.w)*dtv;
        float ux, uy, uz;
        qrotate(Pw, Px, Py, Pz, cax, cay, caz, ux, uy, uz);
        float hdt2 = 0.5f*dtv*dtv;
        Wx += Ux*dtv + ux*hdt2;  Wy += Uy*dtv + uy*hdt2;  Wz += Uz*dtv + uz*hdt2;
        S  += T*dtv + hdt2;
        Ux += ux*dtv; Uy += uy*dtv; Uz += uz*dtv;
        T  += dtv;
        float ew, ex, ey, ez, nw, nx, ny, nz;
        qexpw(wx, wy, wz, ew, ex, ey, ez);
        qmulf(Pw, Px, Py, Pz, ew, ex, ey, ez, nw, nx, ny, nz);
        Pw = nw; Px = nx; Py = ny; Pz = nz;
    }
    float* s = summ + (size_t)c*12;
    ((float4*)s)[0] = make_float4(Pw, Px, Py, Pz);
    ((float4*)s)[1] = make_float4(T, S, Ux, Uy);
    ((float4*)s)[2] = make_float4(Uz, Wx, Wy, Wz);
}

// ---- Kernel 3: per-batch parallel scan of summaries -> chunk-start states ----
__global__ __launch_bounds__(256)
void phaseB(const float* __restrict__ summ, float* __restrict__ state,
            const float* __restrict__ init_pos, const float* __restrict__ init_vel,
            const float* __restrict__ init_rot) {
    __shared__ float lds[256*12];
    int b = blockIdx.x, t = threadIdx.x;
    int c0 = b*CPB + t*SPT;
    Sum s[SPT];
    #pragma unroll
    for (int k = 0; k < SPT; k++) {
        const float* sp = summ + (size_t)(c0+k)*12;
        float4 a0 = ((const float4*)sp)[0];
        float4 a1 = ((const float4*)sp)[1];
        float4 a2 = ((const float4*)sp)[2];
        s[k].Pw = a0.x; s[k].Px = a0.y; s[k].Py = a0.z; s[k].Pz = a0.w;
        s[k].T = a1.x; s[k].S = a1.y; s[k].Ux = a1.z; s[k].Uy = a1.w;
        s[k].Uz = a2.x; s[k].Wx = a2.y; s[k].Wy = a2.z; s[k].Wz = a2.w;
    }
    Sum agg = s[0];
    #pragma unroll
    for (int k = 1; k < SPT; k++) agg = compose(agg, s[k]);

    float* mine = lds + t*12;
    mine[0]=agg.Pw; mine[1]=agg.Px; mine[2]=agg.Py; mine[3]=agg.Pz;
    mine[4]=agg.T;  mine[5]=agg.S;  mine[6]=agg.Ux; mine[7]=agg.Uy;
    mine[8]=agg.Uz; mine[9]=agg.Wx; mine[10]=agg.Wy; mine[11]=agg.Wz;
    __syncthreads();
    for (int d = 1; d < 256; d <<= 1) {
        Sum left;
        bool have = (t >= d);
        if (have) {
            const float* lp = lds + (t-d)*12;
            left.Pw=lp[0]; left.Px=lp[1]; left.Py=lp[2]; left.Pz=lp[3];
            left.T=lp[4];  left.S=lp[5];  left.Ux=lp[6]; left.Uy=lp[7];
            left.Uz=lp[8]; left.Wx=lp[9]; left.Wy=lp[10]; left.Wz=lp[11];
        }
        __syncthreads();
        if (have) {
            agg = compose(left, agg);
            mine[0]=agg.Pw; mine[1]=agg.Px; mine[2]=agg.Py; mine[3]=agg.Pz;
            mine[4]=agg.T;  mine[5]=agg.S;  mine[6]=agg.Ux; mine[7]=agg.Uy;
            mine[8]=agg.Uz; mine[9]=agg.Wx; mine[10]=agg.Wy; mine[11]=agg.Wz;
        }
        __syncthreads();
    }
    State st;
    st.px = init_pos[b*3+0]; st.py = init_pos[b*3+1]; st.pz = init_pos[b*3+2];
    st.vx = init_vel[b*3+0]; st.vy = init_vel[b*3+1]; st.vz = init_vel[b*3+2];
    st.qw = init_rot[b*4+0]; st.qx = init_rot[b*4+1]; st.qy = init_rot[b*4+2]; st.qz = init_rot[b*4+3];
    if (t > 0) {
        const float* lp = lds + (t-1)*12;
        Sum pre;
        pre.Pw=lp[0]; pre.Px=lp[1]; pre.Py=lp[2]; pre.Pz=lp[3];
        pre.T=lp[4];  pre.S=lp[5];  pre.Ux=lp[6]; pre.Uy=lp[7];
        pre.Uz=lp[8]; pre.Wx=lp[9]; pre.Wy=lp[10]; pre.Wz=lp[11];
        st = applySum(st, pre);
    }
    #pragma unroll
    for (int k = 0; k < SPT; k++) {
        float* sp = state + (size_t)(c0+k)*12;
        ((float4*)sp)[0] = make_float4(st.px, st.py, st.pz, st.vx);
        ((float4*)sp)[1] = make_float4(st.vy, st.vz, st.qw, st.qx);
        ((float4*)sp)[2] = make_float4(st.qy, st.qz, 0.0f, 0.0f);
        st = applySum(st, s[k]);
    }
}

// ---- Kernel 4: replay chunk exactly like reference, emit pos/vel/rot ----
__global__ __launch_bounds__(64)
void phaseC(const float* __restrict__ state, const float* __restrict__ acc,
            const float* __restrict__ gyro, const float* __restrict__ dtp,
            float* __restrict__ out) {
    int c = blockIdx.x * 64 + threadIdx.x;
    int b = c / CPB, ci = c % CPB;
    int row0 = b*NF + ci*CL;
    const float* sp = state + (size_t)c*12;
    float4 a0 = ((const float4*)sp)[0];
    float4 a1 = ((const float4*)sp)[1];
    float4 a2 = ((const float4*)sp)[2];
    float px = a0.x, py = a0.y, pz = a0.z;
    float vx = a0.w, vy = a1.x, vz = a1.y;
    float qw = a1.z, qx = a1.w, qy = a2.x, qz = a2.y;
    #pragma unroll
    for (int i = 0; i < CL; i++) {
        int n = row0 + i;
        float* ob = out + (size_t)n*16;
        float2 cA = *(const float2*)(ob+10);
        float4 cB = *(const float4*)(ob+12);
        float dtv = dtp[n];
        float cax = acc[n*3+0] + cA.x;
        float cay = acc[n*3+1] + cA.y;
        float caz = acc[n*3+2] + cB.x;
        float wx = (gyro[n*3+0] + cB.y)*dtv;
        float wy = (gyro[n*3+1] + cB.z)*dtv;
        float wz = (gyro[n*3+2] + cB.w)*dtv;
        float awx, awy, awz;
        qrotate(qw, qx, qy, qz, cax, cay, caz, awx, awy, awz);
        awz += GZ;
        float hdt2 = 0.5f*dtv*dtv;
        px += vx*dtv + awx*hdt2;
        py += vy*dtv + awy*hdt2;
        pz += vz*dtv + awz*hdt2;
        vx += awx*dtv; vy += awy*dtv; vz += awz*dtv;
        float ew, ex, ey, ez, nw, nx, ny, nz;
        qexpw(wx, wy, wz, ew, ex, ey, ez);
        qmulf(qw, qx, qy, qz, ew, ex, ey, ez, nw, nx, ny, nz);
        float inv = 1.0f / sqrtf(nw*nw + nx*nx + ny*ny + nz*nz);
        qw = nw*inv; qx = nx*inv; qy = ny*inv; qz = nz*inv;
        *(float4*)(ob+0) = make_float4(px, py, pz, vx);
        *(float4*)(ob+4) = make_float4(vy, vz, qw, qx);
        *(float2*)(ob+8) = make_float2(qy, qz);
    }
}

extern "C" void kernel_launch(void* const* d_in, const int* in_sizes, int n_in,
                              void* d_out, int out_size, void* d_ws, size_t ws_size,
                              hipStream_t stream) {
    const float* acc      = (const float*)d_in[0];
    const float* gyro     = (const float*)d_in[1];
    const float* dt       = (const float*)d_in[2];
    const float* init_pos = (const float*)d_in[3];
    const float* init_vel = (const float*)d_in[4];
    const float* init_rot = (const float*)d_in[5];
    const float* Wenc     = (const float*)d_in[6];
    const float* benc     = (const float*)d_in[7];
    const float* Wdec     = (const float*)d_in[8];
    const float* bdec     = (const float*)d_in[9];
    float* out = (float*)d_out;
    float* ws  = (float*)d_ws;
    float* summ  = ws + SUMM_OFF;
    float* state = ws + STATE_OFF;
    float* wpack = ws + WPACK_OFF;

    repack_kernel<<<1, NH, 0, stream>>>(Wenc, benc, Wdec, wpack);
    mlp_kernel<<<NROW/256, 256, 0, stream>>>(acc, gyro, wpack, bdec, out);
    phaseA<<<NCHUNK/64, 64, 0, stream>>>(out, acc, gyro, dt, summ);
    phaseB<<<NB, 256, 0, stream>>>(summ, state, init_pos, init_vel, init_rot);
    phaseC<<<NCHUNK/64, 64, 0, stream>>>(state, acc, gyro, dt, out);
}

// Round 3
// 151.327 us; speedup vs baseline: 1.7822x; 1.0118x over previous
//
#include <hip/hip_runtime.h>
#include <math.h>

#define NB 8
#define NF 16384
#define NH 256
#define CL 4                   // steps per chunk
#define CPB (NF / CL)          // 4096 chunks per batch
#define NCHUNK (NB * CPB)      // 32768 chunks
#define NROW (NB * NF)         // 131072 rows
#define SPT (CPB / 256)        // 16 summaries per phaseB thread

#define GZ -9.81007f

// ws layout (floats):
//  rec:   NROW*8     transposed records [i*NCHUNK+c]*8 = ca3, cg3, dt, pad
//  summ:  NCHUNK*12  (P4, T,S,Ux,Uy, Uz,Wx,Wy,Wz)
//  state: NCHUNK*12  (px,py,pz,vx, vy,vz,qw,qx, qy,qz,pad,pad)
#define REC_OFF    0
#define SUMM_OFF   ((size_t)NROW * 8)
#define STATE_OFF  (SUMM_OFF + (size_t)NCHUNK * 12)

__device__ __forceinline__ void qrotate(float qw, float qx, float qy, float qz,
                                        float vx, float vy, float vz,
                                        float& ox, float& oy, float& oz) {
    float tx = qy*vz - qz*vy + qw*vx;
    float ty = qz*vx - qx*vz + qw*vy;
    float tz = qx*vy - qy*vx + qw*vz;
    ox = vx + 2.0f*(qy*tz - qz*ty);
    oy = vy + 2.0f*(qz*tx - qx*tz);
    oz = vz + 2.0f*(qx*ty - qy*tx);
}

__device__ __forceinline__ void qmulf(float aw, float ax, float ay, float az,
                                      float bw, float bx, float by, float bz,
                                      float& ow, float& ox, float& oy, float& oz) {
    ow = aw*bw - ax*bx - ay*by - az*bz;
    ox = aw*bx + bw*ax + (ay*bz - az*by);
    oy = aw*by + bw*ay + (az*bx - ax*bz);
    oz = aw*bz + bw*az + (ax*by - ay*bx);
}

// quat_exp(w), |w| <= ~0.03: fp32-exact Taylor of cos(|w|/2), sin(|w|/2)/|w|.
__device__ __forceinline__ void qexpw(float wx, float wy, float wz,
                                      float& ew, float& ex, float& ey, float& ez) {
    float th2 = wx*wx + wy*wy + wz*wz + 1e-16f;
    float h2  = 0.25f * th2;
    ew = 1.0f + h2*(-0.5f + h2*((1.0f/24.0f) - h2*(1.0f/720.0f)));
    float sh = 0.5f + h2*(-(1.0f/12.0f) + h2*(1.0f/240.0f));
    ex = wx*sh; ey = wy*sh; ez = wz*sh;
}

__device__ __forceinline__ float gelu_tanh(float h) {
    float h2 = h*h;
    float u2 = h*(1.5957691216057308f + 0.0713548162726009f*h2);
    float t  = 1.0f - __fdividef(2.0f, 1.0f + __expf(u2));
    float a  = 0.5f*h;
    return a + a*t;
}

struct Sum { float Pw, Px, Py, Pz, T, S, Ux, Uy, Uz, Wx, Wy, Wz; };

__device__ __forceinline__ Sum compose(const Sum& a, const Sum& b) {
    Sum r;
    float RUx, RUy, RUz, RWx, RWy, RWz;
    qrotate(a.Pw, a.Px, a.Py, a.Pz, b.Ux, b.Uy, b.Uz, RUx, RUy, RUz);
    qrotate(a.Pw, a.Px, a.Py, a.Pz, b.Wx, b.Wy, b.Wz, RWx, RWy, RWz);
    r.Ux = a.Ux + RUx;  r.Uy = a.Uy + RUy;  r.Uz = a.Uz + RUz;
    r.Wx = a.Wx + a.Ux*b.T + RWx;
    r.Wy = a.Wy + a.Uy*b.T + RWy;
    r.Wz = a.Wz + a.Uz*b.T + RWz;
    r.S  = a.S + a.T*b.T + b.S;
    r.T  = a.T + b.T;
    float nw, nx, ny, nz;
    qmulf(a.Pw, a.Px, a.Py, a.Pz, b.Pw, b.Px, b.Py, b.Pz, nw, nx, ny, nz);
    float inv = 1.0f / sqrtf(nw*nw + nx*nx + ny*ny + nz*nz);
    r.Pw = nw*inv; r.Px = nx*inv; r.Py = ny*inv; r.Pz = nz*inv;
    return r;
}

struct State { float px, py, pz, vx, vy, vz, qw, qx, qy, qz; };

__device__ __forceinline__ State applySum(const State& st, const Sum& s) {
    State r;
    float RUx, RUy, RUz, RWx, RWy, RWz;
    qrotate(st.qw, st.qx, st.qy, st.qz, s.Ux, s.Uy, s.Uz, RUx, RUy, RUz);
    qrotate(st.qw, st.qx, st.qy, st.qz, s.Wx, s.Wy, s.Wz, RWx, RWy, RWz);
    r.px = st.px + st.vx*s.T + RWx;
    r.py = st.py + st.vy*s.T + RWy;
    r.pz = st.pz + st.vz*s.T + RWz + GZ*s.S;
    r.vx = st.vx + RUx;
    r.vy = st.vy + RUy;
    r.vz = st.vz + RUz + GZ*s.T;
    float nw, nx, ny, nz;
    qmulf(st.qw, st.qx, st.qy, st.qz, s.Pw, s.Px, s.Py, s.Pz, nw, nx, ny, nz);
    float inv = 1.0f / sqrtf(nw*nw + nx*nx + ny*ny + nz*nz);
    r.qw = nw*inv; r.qx = nx*inv; r.qy = ny*inv; r.qz = nz*inv;
    return r;
}

__device__ __forceinline__ Sum loadSum(const float* __restrict__ p, int c) {
    const float* sp = p + (size_t)c*12;
    float4 a0 = ((const float4*)sp)[0];
    float4 a1 = ((const float4*)sp)[1];
    float4 a2 = ((const float4*)sp)[2];
    Sum s;
    s.Pw = a0.x; s.Px = a0.y; s.Py = a0.z; s.Pz = a0.w;
    s.T = a1.x; s.S = a1.y; s.Ux = a1.z; s.Uy = a1.w;
    s.Uz = a2.x; s.Wx = a2.y; s.Wy = a2.z; s.Wz = a2.w;
    return s;
}

// ---- Kernel 1: MLP. 4 waves/block split the 256 hidden units; 64 rows/block.
__global__ __launch_bounds__(256)
void mlp_kernel(const float* __restrict__ acc, const float* __restrict__ gyro,
                const float* __restrict__ dtp,
                const float* __restrict__ Wenc, const float* __restrict__ benc,
                const float* __restrict__ Wdec, const float* __restrict__ bdec,
                float* __restrict__ out, float* __restrict__ rec) {
    __shared__ float part[4][64][8];
    int t = threadIdx.x;
    int lane = t & 63;
    int wv = __builtin_amdgcn_readfirstlane(t >> 6);   // wave id, forced scalar
    int n = blockIdx.x * 64 + lane;
    float ax = acc[n*3+0], ay = acc[n*3+1], az = acc[n*3+2];
    float gx = gyro[n*3+0], gy = gyro[n*3+1], gz = gyro[n*3+2];
    float c0=0, c1=0, c2=0, c3=0, c4=0, c5=0;
    int j0 = wv * 64;
    #pragma unroll 8
    for (int jj = 0; jj < 64; jj++) {
        int j = j0 + jj;                                // wave-uniform -> s_load
        float w0 = Wenc[0*NH+j], w1 = Wenc[1*NH+j], w2 = Wenc[2*NH+j];
        float w3 = Wenc[3*NH+j], w4 = Wenc[4*NH+j], w5 = Wenc[5*NH+j];
        float h = benc[j] + w0*ax + w1*ay + w2*az + w3*gx + w4*gy + w5*gz;
        float g = gelu_tanh(h);
        const float* dw = Wdec + j*6;
        c0 += g*dw[0]; c1 += g*dw[1]; c2 += g*dw[2];
        c3 += g*dw[3]; c4 += g*dw[4]; c5 += g*dw[5];
    }
    float* pp = part[wv][lane];
    *(float4*)pp     = make_float4(c0, c1, c2, c3);
    *(float2*)(pp+4) = make_float2(c4, c5);
    __syncthreads();
    if (t < 64) {                                       // n == blockIdx*64 + t
        float4 A = *(const float4*)part[0][t];
        float2 B = *(const float2*)(part[0][t]+4);
        #pragma unroll
        for (int w = 1; w < 4; w++) {
            float4 A2 = *(const float4*)part[w][t];
            float2 B2 = *(const float2*)(part[w][t]+4);
            A.x += A2.x; A.y += A2.y; A.z += A2.z; A.w += A2.w;
            B.x += B2.x; B.y += B2.y;
        }
        c0 = A.x + bdec[0]; c1 = A.y + bdec[1]; c2 = A.z + bdec[2];
        c3 = A.w + bdec[3]; c4 = B.x + bdec[4]; c5 = B.y + bdec[5];
        float* ob = out + (size_t)n*16;
        *(float2*)(ob+10) = make_float2(c0, c1);
        *(float4*)(ob+12) = make_float4(c2, c3, c4, c5);
        float dtv = dtp[n];
        int ci = n >> 2, ii = n & 3;                    // CL = 4
        float* rp = rec + (size_t)(ii*NCHUNK + ci)*8;
        *(float4*)rp     = make_float4(c0+ax, c1+ay, c2+az, c3+gx);
        *(float4*)(rp+4) = make_float4(c4+gy, c5+gz, dtv, 0.0f);
    }
}

// ---- Kernel 2: per-chunk summaries, coalesced rec reads ----
__global__ __launch_bounds__(64)
void phaseA(const float* __restrict__ rec, float* __restrict__ summ) {
    int c = blockIdx.x * 64 + threadIdx.x;
    float Pw = 1.0f, Px = 0, Py = 0, Pz = 0;
    float T = 0, S = 0, Ux = 0, Uy = 0, Uz = 0, Wx = 0, Wy = 0, Wz = 0;
    const float4* r = (const float4*)rec;
    #pragma unroll
    for (int i = 0; i < CL; i++) {
        float4 r0 = r[(size_t)(i*NCHUNK + c)*2];
        float4 r1 = r[(size_t)(i*NCHUNK + c)*2 + 1];
        float dtv = r1.z;
        float ux, uy, uz;
        qrotate(Pw, Px, Py, Pz, r0.x, r0.y, r0.z, ux, uy, uz);
        float hdt2 = 0.5f*dtv*dtv;
        Wx += Ux*dtv + ux*hdt2;  Wy += Uy*dtv + uy*hdt2;  Wz += Uz*dtv + uz*hdt2;
        S  += T*dtv + hdt2;
        Ux += ux*dtv; Uy += uy*dtv; Uz += uz*dtv;
        T  += dtv;
        float ew, ex, ey, ez, nw, nx, ny, nz;
        qexpw(r0.w*dtv, r1.x*dtv, r1.y*dtv, ew, ex, ey, ez);
        qmulf(Pw, Px, Py, Pz, ew, ex, ey, ez, nw, nx, ny, nz);
        Pw = nw; Px = nx; Py = ny; Pz = nz;
    }
    float* s = summ + (size_t)c*12;
    ((float4*)s)[0] = make_float4(Pw, Px, Py, Pz);
    ((float4*)s)[1] = make_float4(T, S, Ux, Uy);
    ((float4*)s)[2] = make_float4(Uz, Wx, Wy, Wz);
}

// ---- Kernel 3: per-batch parallel scan of 4096 summaries ----
__global__ __launch_bounds__(256)
void phaseB(const float* __restrict__ summ, float* __restrict__ state,
            const float* __restrict__ init_pos, const float* __restrict__ init_vel,
            const float* __restrict__ init_rot) {
    __shared__ float lds[256*12];
    int b = blockIdx.x, t = threadIdx.x;
    int c0 = b*CPB + t*SPT;
    Sum agg = loadSum(summ, c0);
    for (int k = 1; k < SPT; k++) agg = compose(agg, loadSum(summ, c0+k));

    float* mine = lds + t*12;
    mine[0]=agg.Pw; mine[1]=agg.Px; mine[2]=agg.Py; mine[3]=agg.Pz;
    mine[4]=agg.T;  mine[5]=agg.S;  mine[6]=agg.Ux; mine[7]=agg.Uy;
    mine[8]=agg.Uz; mine[9]=agg.Wx; mine[10]=agg.Wy; mine[11]=agg.Wz;
    __syncthreads();
    for (int d = 1; d < 256; d <<= 1) {
        Sum left;
        bool have = (t >= d);
        if (have) {
            const float* lp = lds + (t-d)*12;
            left.Pw=lp[0]; left.Px=lp[1]; left.Py=lp[2]; left.Pz=lp[3];
            left.T=lp[4];  left.S=lp[5];  left.Ux=lp[6]; left.Uy=lp[7];
            left.Uz=lp[8]; left.Wx=lp[9]; left.Wy=lp[10]; left.Wz=lp[11];
        }
        __syncthreads();
        if (have) {
            agg = compose(left, agg);
            mine[0]=agg.Pw; mine[1]=agg.Px; mine[2]=agg.Py; mine[3]=agg.Pz;
            mine[4]=agg.T;  mine[5]=agg.S;  mine[6]=agg.Ux; mine[7]=agg.Uy;
            mine[8]=agg.Uz; mine[9]=agg.Wx; mine[10]=agg.Wy; mine[11]=agg.Wz;
        }
        __syncthreads();
    }
    State st;
    st.px = init_pos[b*3+0]; st.py = init_pos[b*3+1]; st.pz = init_pos[b*3+2];
    st.vx = init_vel[b*3+0]; st.vy = init_vel[b*3+1]; st.vz = init_vel[b*3+2];
    st.qw = init_rot[b*4+0]; st.qx = init_rot[b*4+1]; st.qy = init_rot[b*4+2]; st.qz = init_rot[b*4+3];
    if (t > 0) {
        const float* lp = lds + (t-1)*12;
        Sum pre;
        pre.Pw=lp[0]; pre.Px=lp[1]; pre.Py=lp[2]; pre.Pz=lp[3];
        pre.T=lp[4];  pre.S=lp[5];  pre.Ux=lp[6]; pre.Uy=lp[7];
        pre.Uz=lp[8]; pre.Wx=lp[9]; pre.Wy=lp[10]; pre.Wz=lp[11];
        st = applySum(st, pre);
    }
    for (int k = 0; k < SPT; k++) {
        float* sp = state + (size_t)(c0+k)*12;
        ((float4*)sp)[0] = make_float4(st.px, st.py, st.pz, st.vx);
        ((float4*)sp)[1] = make_float4(st.vy, st.vz, st.qw, st.qx);
        ((float4*)sp)[2] = make_float4(st.qy, st.qz, 0.0f, 0.0f);
        st = applySum(st, loadSum(summ, c0+k));
    }
}

// ---- Kernel 4: replay chunks; LDS-staged, coalesced output writes ----
__global__ __launch_bounds__(64)
void phaseC(const float* __restrict__ rec, const float* __restrict__ state,
            float* __restrict__ out) {
    __shared__ float lbuf[CL*64*12];            // [i][cc][12]
    int cc = threadIdx.x;
    int c = blockIdx.x * 64 + cc;
    const float* sp = state + (size_t)c*12;
    float4 a0 = ((const float4*)sp)[0];
    float4 a1 = ((const float4*)sp)[1];
    float4 a2 = ((const float4*)sp)[2];
    float px = a0.x, py = a0.y, pz = a0.z;
    float vx = a0.w, vy = a1.x, vz = a1.y;
    float qw = a1.z, qx = a1.w, qy = a2.x, qz = a2.y;
    const float4* r = (const float4*)rec;
    #pragma unroll
    for (int i = 0; i < CL; i++) {
        float4 r0 = r[(size_t)(i*NCHUNK + c)*2];
        float4 r1 = r[(size_t)(i*NCHUNK + c)*2 + 1];
        float dtv = r1.z;
        float awx, awy, awz;
        qrotate(qw, qx, qy, qz, r0.x, r0.y, r0.z, awx, awy, awz);
        awz += GZ;
        float hdt2 = 0.5f*dtv*dtv;
        px += vx*dtv + awx*hdt2;
        py += vy*dtv + awy*hdt2;
        pz += vz*dtv + awz*hdt2;
        vx += awx*dtv; vy += awy*dtv; vz += awz*dtv;
        float ew, ex, ey, ez, nw, nx, ny, nz;
        qexpw(r0.w*dtv, r1.x*dtv, r1.y*dtv, ew, ex, ey, ez);
        qmulf(qw, qx, qy, qz, ew, ex, ey, ez, nw, nx, ny, nz);
        float inv = 1.0f / sqrtf(nw*nw + nx*nx + ny*ny + nz*nz);
        qw = nw*inv; qx = nx*inv; qy = ny*inv; qz = nz*inv;
        float* lp = lbuf + (size_t)(i*64 + cc)*12;
        *(float4*)(lp+0) = make_float4(px, py, pz, vx);
        *(float4*)(lp+4) = make_float4(vy, vz, qw, qx);
        *(float4*)(lp+8) = make_float4(qy, qz, 0.0f, 0.0f);
    }
    __syncthreads();
    int row0 = blockIdx.x * 64 * CL;            // 256 contiguous rows
    #pragma unroll
    for (int g = 0; g < CL; g++) {
        int rr = g*64 + cc;
        int cc2 = rr >> 2, i2 = rr & 3;
        const float* lp = lbuf + (size_t)(i2*64 + cc2)*12;
        float4 o0 = *(const float4*)(lp+0);
        float4 o1 = *(const float4*)(lp+4);
        float2 o2 = *(const float2*)(lp+8);
        float* ob = out + (size_t)(row0 + rr)*16;
        *(float4*)(ob+0) = o0;
        *(float4*)(ob+4) = o1;
        *(float2*)(ob+8) = o2;
    }
}

extern "C" void kernel_launch(void* const* d_in, const int* in_sizes, int n_in,
                              void* d_out, int out_size, void* d_ws, size_t ws_size,
                              hipStream_t stream) {
    const float* acc      = (const float*)d_in[0];
    const float* gyro     = (const float*)d_in[1];
    const float* dt       = (const float*)d_in[2];
    const float* init_pos = (const float*)d_in[3];
    const float* init_vel = (const float*)d_in[4];
    const float* init_rot = (const float*)d_in[5];
    const float* Wenc     = (const float*)d_in[6];
    const float* benc     = (const float*)d_in[7];
    const float* Wdec     = (const float*)d_in[8];
    const float* bdec     = (const float*)d_in[9];
    float* out = (float*)d_out;
    float* ws  = (float*)d_ws;
    float* rec   = ws + REC_OFF;
    float* summ  = ws + SUMM_OFF;
    float* state = ws + STATE_OFF;

    mlp_kernel<<<NROW/64, 256, 0, stream>>>(acc, gyro, dt, Wenc, benc, Wdec, bdec, out, rec);
    phaseA<<<NCHUNK/64, 64, 0, stream>>>(rec, summ);
    phaseB<<<NB, 256, 0, stream>>>(summ, state, init_pos, init_vel, init_rot);
    phaseC<<<NCHUNK/64, 64, 0, stream>>>(rec, state, out);
}

// Round 4
// 148.026 us; speedup vs baseline: 1.8219x; 1.0223x over previous
//
#include <hip/hip_runtime.h>
#include <math.h>

#define NB 8
#define NF 16384
#define NH 256
#define CL 4                   // steps per chunk
#define CPB (NF / CL)          // 4096 chunks per batch
#define NCHUNK (NB * CPB)      // 32768 chunks
#define NROW (NB * NF)         // 131072 rows
#define SPT (CPB / 256)        // 16 summaries per phaseB thread

#define GZ -9.81007f

// ws layout (floats):
//  rec:   NROW*8     transposed records [i*NCHUNK+c]*8 = ca3, cg3, dt, pad
//  summ:  NCHUNK*12  (P4, T,S,Ux,Uy, Uz,Wx,Wy,Wz)
//  state: NCHUNK*12  (px,py,pz,vx, vy,vz,qw,qx, qy,qz,pad,pad)
#define REC_OFF    0
#define SUMM_OFF   ((size_t)NROW * 8)
#define STATE_OFF  (SUMM_OFF + (size_t)NCHUNK * 12)

__device__ __forceinline__ void qrotate(float qw, float qx, float qy, float qz,
                                        float vx, float vy, float vz,
                                        float& ox, float& oy, float& oz) {
    float tx = qy*vz - qz*vy + qw*vx;
    float ty = qz*vx - qx*vz + qw*vy;
    float tz = qx*vy - qy*vx + qw*vz;
    ox = vx + 2.0f*(qy*tz - qz*ty);
    oy = vy + 2.0f*(qz*tx - qx*tz);
    oz = vz + 2.0f*(qx*ty - qy*tx);
}

__device__ __forceinline__ void qmulf(float aw, float ax, float ay, float az,
                                      float bw, float bx, float by, float bz,
                                      float& ow, float& ox, float& oy, float& oz) {
    ow = aw*bw - ax*bx - ay*by - az*bz;
    ox = aw*bx + bw*ax + (ay*bz - az*by);
    oy = aw*by + bw*ay + (az*bx - ax*bz);
    oz = aw*bz + bw*az + (ax*by - ay*bx);
}

// quat_exp(w), |w| <= ~0.03: fp32-exact Taylor of cos(|w|/2), sin(|w|/2)/|w|.
__device__ __forceinline__ void qexpw(float wx, float wy, float wz,
                                      float& ew, float& ex, float& ey, float& ez) {
    float th2 = wx*wx + wy*wy + wz*wz + 1e-16f;
    float h2  = 0.25f * th2;
    ew = 1.0f + h2*(-0.5f + h2*((1.0f/24.0f) - h2*(1.0f/720.0f)));
    float sh = 0.5f + h2*(-(1.0f/12.0f) + h2*(1.0f/240.0f));
    ex = wx*sh; ey = wy*sh; ez = wz*sh;
}

__device__ __forceinline__ float gelu_tanh(float h) {
    float h2 = h*h;
    float u2 = h*(1.5957691216057308f + 0.0713548162726009f*h2);
    float t  = 1.0f - __fdividef(2.0f, 1.0f + __expf(u2));
    float a  = 0.5f*h;
    return a + a*t;
}

struct Sum { float Pw, Px, Py, Pz, T, S, Ux, Uy, Uz, Wx, Wy, Wz; };

__device__ __forceinline__ Sum compose(const Sum& a, const Sum& b) {
    Sum r;
    float RUx, RUy, RUz, RWx, RWy, RWz;
    qrotate(a.Pw, a.Px, a.Py, a.Pz, b.Ux, b.Uy, b.Uz, RUx, RUy, RUz);
    qrotate(a.Pw, a.Px, a.Py, a.Pz, b.Wx, b.Wy, b.Wz, RWx, RWy, RWz);
    r.Ux = a.Ux + RUx;  r.Uy = a.Uy + RUy;  r.Uz = a.Uz + RUz;
    r.Wx = a.Wx + a.Ux*b.T + RWx;
    r.Wy = a.Wy + a.Uy*b.T + RWy;
    r.Wz = a.Wz + a.Uz*b.T + RWz;
    r.S  = a.S + a.T*b.T + b.S;
    r.T  = a.T + b.T;
    float nw, nx, ny, nz;
    qmulf(a.Pw, a.Px, a.Py, a.Pz, b.Pw, b.Px, b.Py, b.Pz, nw, nx, ny, nz);
    float inv = 1.0f / sqrtf(nw*nw + nx*nx + ny*ny + nz*nz);
    r.Pw = nw*inv; r.Px = nx*inv; r.Py = ny*inv; r.Pz = nz*inv;
    return r;
}

__device__ __forceinline__ Sum shflDownSum(const Sum& s, int d) {
    Sum r;
    r.Pw = __shfl_down(s.Pw, d, 64); r.Px = __shfl_down(s.Px, d, 64);
    r.Py = __shfl_down(s.Py, d, 64); r.Pz = __shfl_down(s.Pz, d, 64);
    r.T  = __shfl_down(s.T,  d, 64); r.S  = __shfl_down(s.S,  d, 64);
    r.Ux = __shfl_down(s.Ux, d, 64); r.Uy = __shfl_down(s.Uy, d, 64);
    r.Uz = __shfl_down(s.Uz, d, 64); r.Wx = __shfl_down(s.Wx, d, 64);
    r.Wy = __shfl_down(s.Wy, d, 64); r.Wz = __shfl_down(s.Wz, d, 64);
    return r;
}

struct State { float px, py, pz, vx, vy, vz, qw, qx, qy, qz; };

__device__ __forceinline__ State applySum(const State& st, const Sum& s) {
    State r;
    float RUx, RUy, RUz, RWx, RWy, RWz;
    qrotate(st.qw, st.qx, st.qy, st.qz, s.Ux, s.Uy, s.Uz, RUx, RUy, RUz);
    qrotate(st.qw, st.qx, st.qy, st.qz, s.Wx, s.Wy, s.Wz, RWx, RWy, RWz);
    r.px = st.px + st.vx*s.T + RWx;
    r.py = st.py + st.vy*s.T + RWy;
    r.pz = st.pz + st.vz*s.T + RWz + GZ*s.S;
    r.vx = st.vx + RUx;
    r.vy = st.vy + RUy;
    r.vz = st.vz + RUz + GZ*s.T;
    float nw, nx, ny, nz;
    qmulf(st.qw, st.qx, st.qy, st.qz, s.Pw, s.Px, s.Py, s.Pz, nw, nx, ny, nz);
    float inv = 1.0f / sqrtf(nw*nw + nx*nx + ny*ny + nz*nz);
    r.qw = nw*inv; r.qx = nx*inv; r.qy = ny*inv; r.qz = nz*inv;
    return r;
}

__device__ __forceinline__ Sum loadSum(const float* __restrict__ p, int c) {
    const float* sp = p + (size_t)c*12;
    float4 a0 = ((const float4*)sp)[0];
    float4 a1 = ((const float4*)sp)[1];
    float4 a2 = ((const float4*)sp)[2];
    Sum s;
    s.Pw = a0.x; s.Px = a0.y; s.Py = a0.z; s.Pz = a0.w;
    s.T = a1.x; s.S = a1.y; s.Ux = a1.z; s.Uy = a1.w;
    s.Uz = a2.x; s.Wx = a2.y; s.Wy = a2.z; s.Wz = a2.w;
    return s;
}

// ---- Kernel 1: MLP + record pack + per-chunk summaries (fused phaseA).
// 4 waves/block split 256 hidden units; 64 rows/block = 16 whole chunks.
__global__ __launch_bounds__(256)
void mlp_summ_kernel(const float* __restrict__ acc, const float* __restrict__ gyro,
                     const float* __restrict__ dtp,
                     const float* __restrict__ Wenc, const float* __restrict__ benc,
                     const float* __restrict__ Wdec, const float* __restrict__ bdec,
                     float* __restrict__ out, float* __restrict__ rec,
                     float* __restrict__ summ) {
    __shared__ float part[4][64][8];
    int t = threadIdx.x;
    int lane = t & 63;
    int wv = __builtin_amdgcn_readfirstlane(t >> 6);   // wave id, forced scalar
    int n = blockIdx.x * 64 + lane;
    float ax = acc[n*3+0], ay = acc[n*3+1], az = acc[n*3+2];
    float gx = gyro[n*3+0], gy = gyro[n*3+1], gz = gyro[n*3+2];
    float c0=0, c1=0, c2=0, c3=0, c4=0, c5=0;
    int j0 = wv * 64;
    #pragma unroll 8
    for (int jj = 0; jj < 64; jj++) {
        int j = j0 + jj;                                // wave-uniform -> s_load
        float w0 = Wenc[0*NH+j], w1 = Wenc[1*NH+j], w2 = Wenc[2*NH+j];
        float w3 = Wenc[3*NH+j], w4 = Wenc[4*NH+j], w5 = Wenc[5*NH+j];
        float h = benc[j] + w0*ax + w1*ay + w2*az + w3*gx + w4*gy + w5*gz;
        float g = gelu_tanh(h);
        const float* dw = Wdec + j*6;
        c0 += g*dw[0]; c1 += g*dw[1]; c2 += g*dw[2];
        c3 += g*dw[3]; c4 += g*dw[4]; c5 += g*dw[5];
    }
    float* pp = part[wv][lane];
    *(float4*)pp     = make_float4(c0, c1, c2, c3);
    *(float2*)(pp+4) = make_float2(c4, c5);
    __syncthreads();
    if (t < 64) {                                       // wave 0: n = blockIdx*64 + t
        float4 A = *(const float4*)part[0][t];
        float2 B = *(const float2*)(part[0][t]+4);
        #pragma unroll
        for (int w = 1; w < 4; w++) {
            float4 A2 = *(const float4*)part[w][t];
            float2 B2 = *(const float2*)(part[w][t]+4);
            A.x += A2.x; A.y += A2.y; A.z += A2.z; A.w += A2.w;
            B.x += B2.x; B.y += B2.y;
        }
        c0 = A.x + bdec[0]; c1 = A.y + bdec[1]; c2 = A.z + bdec[2];
        c3 = A.w + bdec[3]; c4 = B.x + bdec[4]; c5 = B.y + bdec[5];
        float* ob = out + (size_t)n*16;
        *(float2*)(ob+10) = make_float2(c0, c1);
        *(float4*)(ob+12) = make_float4(c2, c3, c4, c5);
        float dtv = dtp[n];
        float cax = c0+ax, cay = c1+ay, caz = c2+az;
        float cgx = c3+gx, cgy = c4+gy, cgz = c5+gz;
        int ci = n >> 2, ii = n & 3;                    // CL = 4
        float* rp = rec + (size_t)(ii*NCHUNK + ci)*8;
        *(float4*)rp     = make_float4(cax, cay, caz, cgx);
        *(float4*)(rp+4) = make_float4(cgy, cgz, dtv, 0.0f);

        // per-step summary for this row
        Sum s;
        float hdt2 = 0.5f*dtv*dtv;
        qexpw(cgx*dtv, cgy*dtv, cgz*dtv, s.Pw, s.Px, s.Py, s.Pz);
        s.T = dtv; s.S = hdt2;
        s.Ux = cax*dtv;  s.Uy = cay*dtv;  s.Uz = caz*dtv;
        s.Wx = cax*hdt2; s.Wy = cay*hdt2; s.Wz = caz*hdt2;
        // tree-compose 4 consecutive lanes -> chunk summary at lane%4==0
        Sum nb = shflDownSum(s, 1);
        s = compose(s, nb);          // valid at even lanes
        nb = shflDownSum(s, 2);
        s = compose(s, nb);          // valid at lane%4==0
        if ((t & 3) == 0) {
            float* sp = summ + (size_t)(n >> 2)*12;
            ((float4*)sp)[0] = make_float4(s.Pw, s.Px, s.Py, s.Pz);
            ((float4*)sp)[1] = make_float4(s.T, s.S, s.Ux, s.Uy);
            ((float4*)sp)[2] = make_float4(s.Uz, s.Wx, s.Wy, s.Wz);
        }
    }
}

// ---- Kernel 2: per-batch parallel scan of 4096 summaries ----
__global__ __launch_bounds__(256)
void phaseB(const float* __restrict__ summ, float* __restrict__ state,
            const float* __restrict__ init_pos, const float* __restrict__ init_vel,
            const float* __restrict__ init_rot) {
    __shared__ float lds[256*12];
    int b = blockIdx.x, t = threadIdx.x;
    int c0 = b*CPB + t*SPT;
    Sum agg = loadSum(summ, c0);
    for (int k = 1; k < SPT; k++) agg = compose(agg, loadSum(summ, c0+k));

    float* mine = lds + t*12;
    mine[0]=agg.Pw; mine[1]=agg.Px; mine[2]=agg.Py; mine[3]=agg.Pz;
    mine[4]=agg.T;  mine[5]=agg.S;  mine[6]=agg.Ux; mine[7]=agg.Uy;
    mine[8]=agg.Uz; mine[9]=agg.Wx; mine[10]=agg.Wy; mine[11]=agg.Wz;
    __syncthreads();
    for (int d = 1; d < 256; d <<= 1) {
        Sum left;
        bool have = (t >= d);
        if (have) {
            const float* lp = lds + (t-d)*12;
            left.Pw=lp[0]; left.Px=lp[1]; left.Py=lp[2]; left.Pz=lp[3];
            left.T=lp[4];  left.S=lp[5];  left.Ux=lp[6]; left.Uy=lp[7];
            left.Uz=lp[8]; left.Wx=lp[9]; left.Wy=lp[10]; left.Wz=lp[11];
        }
        __syncthreads();
        if (have) {
            agg = compose(left, agg);
            mine[0]=agg.Pw; mine[1]=agg.Px; mine[2]=agg.Py; mine[3]=agg.Pz;
            mine[4]=agg.T;  mine[5]=agg.S;  mine[6]=agg.Ux; mine[7]=agg.Uy;
            mine[8]=agg.Uz; mine[9]=agg.Wx; mine[10]=agg.Wy; mine[11]=agg.Wz;
        }
        __syncthreads();
    }
    State st;
    st.px = init_pos[b*3+0]; st.py = init_pos[b*3+1]; st.pz = init_pos[b*3+2];
    st.vx = init_vel[b*3+0]; st.vy = init_vel[b*3+1]; st.vz = init_vel[b*3+2];
    st.qw = init_rot[b*4+0]; st.qx = init_rot[b*4+1]; st.qy = init_rot[b*4+2]; st.qz = init_rot[b*4+3];
    if (t > 0) {
        const float* lp = lds + (t-1)*12;
        Sum pre;
        pre.Pw=lp[0]; pre.Px=lp[1]; pre.Py=lp[2]; pre.Pz=lp[3];
        pre.T=lp[4];  pre.S=lp[5];  pre.Ux=lp[6]; pre.Uy=lp[7];
        pre.Uz=lp[8]; pre.Wx=lp[9]; pre.Wy=lp[10]; pre.Wz=lp[11];
        st = applySum(st, pre);
    }
    for (int k = 0; k < SPT; k++) {
        float* sp = state + (size_t)(c0+k)*12;
        ((float4*)sp)[0] = make_float4(st.px, st.py, st.pz, st.vx);
        ((float4*)sp)[1] = make_float4(st.vy, st.vz, st.qw, st.qx);
        ((float4*)sp)[2] = make_float4(st.qy, st.qz, 0.0f, 0.0f);
        st = applySum(st, loadSum(summ, c0+k));
    }
}

// ---- Kernel 3: replay chunks, direct row writes (L2 merges the 64B rows) ----
__global__ __launch_bounds__(256)
void phaseC(const float* __restrict__ rec, const float* __restrict__ state,
            float* __restrict__ out) {
    int c = blockIdx.x * 256 + threadIdx.x;
    const float* sp = state + (size_t)c*12;
    float4 a0 = ((const float4*)sp)[0];
    float4 a1 = ((const float4*)sp)[1];
    float4 a2 = ((const float4*)sp)[2];
    float px = a0.x, py = a0.y, pz = a0.z;
    float vx = a0.w, vy = a1.x, vz = a1.y;
    float qw = a1.z, qx = a1.w, qy = a2.x, qz = a2.y;
    const float4* r = (const float4*)rec;
    float* obase = out + (size_t)c*CL*16;
    #pragma unroll
    for (int i = 0; i < CL; i++) {
        float4 r0 = r[(size_t)(i*NCHUNK + c)*2];
        float4 r1 = r[(size_t)(i*NCHUNK + c)*2 + 1];
        float dtv = r1.z;
        float awx, awy, awz;
        qrotate(qw, qx, qy, qz, r0.x, r0.y, r0.z, awx, awy, awz);
        awz += GZ;
        float hdt2 = 0.5f*dtv*dtv;
        px += vx*dtv + awx*hdt2;
        py += vy*dtv + awy*hdt2;
        pz += vz*dtv + awz*hdt2;
        vx += awx*dtv; vy += awy*dtv; vz += awz*dtv;
        float ew, ex, ey, ez, nw, nx, ny, nz;
        qexpw(r0.w*dtv, r1.x*dtv, r1.y*dtv, ew, ex, ey, ez);
        qmulf(qw, qx, qy, qz, ew, ex, ey, ez, nw, nx, ny, nz);
        float inv = 1.0f / sqrtf(nw*nw + nx*nx + ny*ny + nz*nz);
        qw = nw*inv; qx = nx*inv; qy = ny*inv; qz = nz*inv;
        float* ob = obase + (size_t)i*16;
        *(float4*)(ob+0) = make_float4(px, py, pz, vx);
        *(float4*)(ob+4) = make_float4(vy, vz, qw, qx);
        *(float2*)(ob+8) = make_float2(qy, qz);
    }
}

extern "C" void kernel_launch(void* const* d_in, const int* in_sizes, int n_in,
                              void* d_out, int out_size, void* d_ws, size_t ws_size,
                              hipStream_t stream) {
    const float* acc      = (const float*)d_in[0];
    const float* gyro     = (const float*)d_in[1];
    const float* dt       = (const float*)d_in[2];
    const float* init_pos = (const float*)d_in[3];
    const float* init_vel = (const float*)d_in[4];
    const float* init_rot = (const float*)d_in[5];
    const float* Wenc     = (const float*)d_in[6];
    const float* benc     = (const float*)d_in[7];
    const float* Wdec     = (const float*)d_in[8];
    const float* bdec     = (const float*)d_in[9];
    float* out = (float*)d_out;
    float* ws  = (float*)d_ws;
    float* rec   = ws + REC_OFF;
    float* summ  = ws + SUMM_OFF;
    float* state = ws + STATE_OFF;

    mlp_summ_kernel<<<NROW/64, 256, 0, stream>>>(acc, gyro, dt, Wenc, benc, Wdec, bdec,
                                                 out, rec, summ);
    phaseB<<<NB, 256, 0, stream>>>(summ, state, init_pos, init_vel, init_rot);
    phaseC<<<NCHUNK/256, 256, 0, stream>>>(rec, state, out);
}